// Round 1
// baseline (570.628 us; speedup 1.0000x reference)
//
#include <hip/hip_runtime.h>
#include <hip/hip_bf16.h>

typedef __bf16 bf16x4 __attribute__((ext_vector_type(4)));
typedef __bf16 bf16x8 __attribute__((ext_vector_type(8)));
typedef float  floatx4 __attribute__((ext_vector_type(4)));

// ---------------------------------------------------------------------------
// Kernel 1: Cayley transform + bf16 MFMA-fragment packing.
//   Q = (I + S)(I - S)^{-1} = 2*(I - S)^{-1} - I,  S = 0.5*(M - M^T)
// Pivot-free Gauss-Jordan is stable here: every pivot >= 1 (Schur complement
// of I - S has symmetric part I + PSD).
// Blocks 0..63: R -> w1pack (stage-1 weights); 64..127: L -> w2pack.
// Packed layout per matrix (4096 bf16):
//   dst[(kh*4+grp)*512 + lane*8 + j] = Q[16*grp + (lane&15)][32*kh + 8*(lane>>4) + j]
// which is exactly the mfma_f32_16x16x32_bf16 B-fragment load order.
// ---------------------------------------------------------------------------
__global__ __launch_bounds__(256) void cayley_pack_kernel(
    const float* __restrict__ L, const float* __restrict__ R,
    __bf16* __restrict__ ws) {
  __shared__ float Ms[64][65];
  __shared__ float Pa[64];
  __shared__ float Pi[64];
  __shared__ float fcol[2][64];

  const int blk = blockIdx.x;
  const int t = threadIdx.x;
  const float* M = (blk < 64) ? (R + (size_t)blk * 4096)
                              : (L + (size_t)(blk - 64) * 4096);
  __bf16* dst = ws + (size_t)blk * 4096;

  for (int u = 0; u < 16; ++u) {
    int idx = u * 256 + t;
    Ms[idx >> 6][idx & 63] = M[idx];
  }
  __syncthreads();

  const int i = t >> 2;        // row 0..63 (4 threads per row, same wave)
  const int g = t & 3;         // column group
  const int jb = g * 16;
  float a[16], v[16];
#pragma unroll
  for (int jj = 0; jj < 16; ++jj) {
    int j = jb + jj;
    float s = 0.5f * (Ms[i][j] - Ms[j][i]);
    a[jj] = (i == j ? 1.0f : 0.0f) - s;   // A = I - S
    v[jj] = (i == j ? 1.0f : 0.0f);       // Inv = I
  }
  __syncthreads();

#pragma unroll
  for (int k = 0; k < 64; ++k) {
    // ph1: publish column k (f values; fcol[k][k] is the pivot)
    if (g == (k >> 4)) fcol[k & 1][i] = a[k & 15];
    __syncthreads();
    // ph2: pivot row scales itself and publishes
    if (i == k) {
      float ip = 1.0f / fcol[k & 1][k];
#pragma unroll
      for (int jj = 0; jj < 16; ++jj) {
        a[jj] *= ip; v[jj] *= ip;
        Pa[jb + jj] = a[jj]; Pi[jb + jj] = v[jj];
      }
    }
    __syncthreads();
    // ph3: eliminate
    if (i != k) {
      float f = fcol[k & 1][i];
#pragma unroll
      for (int jj = 0; jj < 16; ++jj) {
        a[jj] -= f * Pa[jb + jj];
        v[jj] -= f * Pi[jb + jj];
      }
    }
  }

  // Q = 2*Ainv - I staged to LDS for the packing shuffle
#pragma unroll
  for (int jj = 0; jj < 16; ++jj) {
    int j = jb + jj;
    Ms[i][j] = 2.0f * v[jj] - (i == j ? 1.0f : 0.0f);
  }
  __syncthreads();

  const int lane = t & 63;
  const int grp = t >> 6;
  const int colq = lane & 15;
  const int quad = lane >> 4;
#pragma unroll
  for (int kh = 0; kh < 2; ++kh) {
    bf16x8 pk;
#pragma unroll
    for (int j8 = 0; j8 < 8; ++j8)
      pk[j8] = (__bf16)Ms[16 * grp + colq][32 * kh + 8 * quad + j8];
    *(bf16x8*)(dst + (kh * 4 + grp) * 512 + lane * 8) = pk;
  }
}

// ---------------------------------------------------------------------------
// Kernel 2: fused butterfly. Each workgroup (256 thr = 4 waves) owns 8 batch
// rows. Stage 1: out1[b,r,q] = sum_p x[b,r*64+p]*w1[r,q,p] -> LDS inter[l=q][b][r]
// (bf16, 64KB, XOR chunk swizzle). One barrier. Stage 2:
// out[b, s*64+l] = sum_r inter[b,l,r]*w2[l,s,r], with an in-register
// l-transpose so global stores are 64B-contiguous per lane.
// MFMA layouts (gfx950 16x16x32_bf16): A[m=lane&15][k=(lane>>4)*8+j],
// B[k=(lane>>4)*8+j][n=lane&15], C col=lane&15 row=(lane>>4)*4+reg.
// ---------------------------------------------------------------------------
__global__ __launch_bounds__(256, 2) void butterfly_kernel(
    const float* __restrict__ x, const __bf16* __restrict__ ws,
    float* __restrict__ out) {
  __shared__ short interS[32768];          // exactly 64 KB -> 2 blocks/CU
  __bf16* inter = (__bf16*)interS;

  const int t = threadIdx.x;
  const int wv = t >> 6;                   // wave 0..3
  const int lane = t & 63;
  const int col = lane & 15;
  const int quad = lane >> 4;
  const size_t b0 = (size_t)blockIdx.x * 8;

  const __bf16* w1 = ws;                   // cayley(R), stage-1 weights
  const __bf16* w2 = ws + 64 * 4096;       // cayley(L), stage-2 weights

  // ---------------- stage 1: wave wv owns r in [16*wv, 16*wv+16) ----------
  const float* xrow = x + (b0 + (size_t)(col & 7)) * 4096;
#pragma unroll
  for (int rg = 0; rg < 4; ++rg) {
    const int r0 = wv * 16 + rg * 4;
    bf16x8 afrag[4][2];
#pragma unroll
    for (int ir = 0; ir < 4; ++ir) {
      const float* src = xrow + (r0 + ir) * 64 + quad * 8;
#pragma unroll
      for (int kh = 0; kh < 2; ++kh) {
        floatx4 u = *(const floatx4*)(src + kh * 32);
        floatx4 w = *(const floatx4*)(src + kh * 32 + 4);
        bf16x8 f;
        f[0] = (__bf16)u[0]; f[1] = (__bf16)u[1];
        f[2] = (__bf16)u[2]; f[3] = (__bf16)u[3];
        f[4] = (__bf16)w[0]; f[5] = (__bf16)w[1];
        f[6] = (__bf16)w[2]; f[7] = (__bf16)w[3];
        afrag[ir][kh] = f;
      }
    }
#pragma unroll
    for (int qc = 0; qc < 4; ++qc) {
      floatx4 vals[4];
#pragma unroll
      for (int ir = 0; ir < 4; ++ir) {
        const int r = r0 + ir;
        bf16x8 bf0 = *(const bf16x8*)(w1 + (size_t)r * 4096 + (0 * 4 + qc) * 512 + lane * 8);
        bf16x8 bf1 = *(const bf16x8*)(w1 + (size_t)r * 4096 + (1 * 4 + qc) * 512 + lane * 8);
        floatx4 acc = {0.f, 0.f, 0.f, 0.f};
        acc = __builtin_amdgcn_mfma_f32_16x16x32_bf16(afrag[ir][0], bf0, acc, 0, 0, 0);
        acc = __builtin_amdgcn_mfma_f32_16x16x32_bf16(afrag[ir][1], bf1, acc, 0, 0, 0);
        vals[ir] = acc;
      }
      if (quad < 2) {                       // C rows 0..7 are the valid batch rows
        const int l = qc * 16 + col;        // l = q
        const int c = r0 >> 3;              // 8-elem chunk index
        const int ls = l & 7;
#pragma unroll
        for (int reg = 0; reg < 4; ++reg) {
          const int b = quad * 4 + reg;     // 0..7
          bf16x4 pk;
          pk[0] = (__bf16)vals[0][reg];
          pk[1] = (__bf16)vals[1][reg];
          pk[2] = (__bf16)vals[2][reg];
          pk[3] = (__bf16)vals[3][reg];
          const int cs = c ^ b ^ ls;        // bank swizzle
          *(bf16x4*)(inter + l * 512 + b * 64 + cs * 8 + (r0 & 7)) = pk;
        }
      }
    }
  }
  __syncthreads();

  // ---------------- stage 2: wave wv owns l in [16*wv, 16*wv+16) ----------
  const int b = col & 7;                    // A-frag row (dup for col>=8)
  float* outb = out + b0 * 4096;
#pragma unroll
  for (int sc = 0; sc < 4; ++sc) {
    floatx4 vals[16];
#pragma unroll
    for (int l16 = 0; l16 < 16; ++l16) {
      const int l = wv * 16 + l16;
      const int swz = b ^ (l & 7);
      bf16x8 a0 = *(const bf16x8*)(inter + l * 512 + b * 64 + (quad ^ swz) * 8);
      bf16x8 a1 = *(const bf16x8*)(inter + l * 512 + b * 64 + ((4 + quad) ^ swz) * 8);
      bf16x8 bf0 = *(const bf16x8*)(w2 + (size_t)l * 4096 + (0 * 4 + sc) * 512 + lane * 8);
      bf16x8 bf1 = *(const bf16x8*)(w2 + (size_t)l * 4096 + (1 * 4 + sc) * 512 + lane * 8);
      floatx4 acc = {0.f, 0.f, 0.f, 0.f};
      acc = __builtin_amdgcn_mfma_f32_16x16x32_bf16(a0, bf0, acc, 0, 0, 0);
      acc = __builtin_amdgcn_mfma_f32_16x16x32_bf16(a1, bf1, acc, 0, 0, 0);
      vals[l16] = acc;
    }
    if (quad < 2) {
      const int s = sc * 16 + col;
#pragma unroll
      for (int reg = 0; reg < 4; ++reg) {
        const int bb = quad * 4 + reg;      // batch row 0..7
        float* dstp = outb + (size_t)bb * 4096 + s * 64 + wv * 16;
#pragma unroll
        for (int q4 = 0; q4 < 4; ++q4) {    // 64B contiguous per (bb,s)
          floatx4 vv;
          vv[0] = vals[q4 * 4 + 0][reg];
          vv[1] = vals[q4 * 4 + 1][reg];
          vv[2] = vals[q4 * 4 + 2][reg];
          vv[3] = vals[q4 * 4 + 3][reg];
          *(floatx4*)(dstp + q4 * 4) = vv;
        }
      }
    }
  }
}

extern "C" void kernel_launch(void* const* d_in, const int* in_sizes, int n_in,
                              void* d_out, int out_size, void* d_ws, size_t ws_size,
                              hipStream_t stream) {
  const float* x = (const float*)d_in[0];
  const float* L = (const float*)d_in[1];
  const float* R = (const float*)d_in[2];
  float* out = (float*)d_out;
  __bf16* ws = (__bf16*)d_ws;               // needs 128*4096*2 = 1 MB

  const int nrows = in_sizes[0] / 4096;     // 16384

  cayley_pack_kernel<<<128, 256, 0, stream>>>(L, R, ws);
  butterfly_kernel<<<nrows / 8, 256, 0, stream>>>(x, ws, out);
}